// Round 14
// baseline (98.400 us; speedup 1.0000x reference)
//
#include <hip/hip_runtime.h>
#include <math.h>

// ---------------------------------------------------------------------------
// QMixer forward, round 14: FUSED attn+hyper.
// r13 accounting: attn 35us@134MB + hyper 38us@110MB + setup/gaps 12 = 88.7;
// both at ~60% achievable BW (effective-BW ceiling, occupancy-insensitive for
// 3 rounds). Remaining lever is TRAFFIC: hyper re-reads states-ally (67MB) +
// ao round-trip (8MB). Fused: one 512-thr kernel, 64 tok/block, grid 512
// (exactly 2 blocks/CU, no tail). Phases: stage CAT|WQKT -> attn(8 tok/wave,
// ao -> per-wave LDS) -> stage ZBRT -> zbr (mm via reg-gather; r12: = LDS) ->
// stage H1T|W2T|WFT -> wf + h1/w1 chunks. 5 barriers per 64 tokens (r4 had
// 3 per 16 on 4 waves). LDS 74KB -> 2 blocks/CU. b1/wf interface bf16 in the
// dead tmp-tile region. HBM traffic ~277 -> ~202 MB.
// ---------------------------------------------------------------------------

#define TOKS 32768

typedef __attribute__((ext_vector_type(8))) short short8;
typedef __attribute__((ext_vector_type(4))) float f32x4;

#define MFMA(a, b, c) __builtin_amdgcn_mfma_f32_16x16x32_bf16((a), (b), (c), 0, 0, 0)

// ws element offsets (ushort units for bf16 part) -- all regions SWIZZLED
#define E_CAT   0          // [64][128]
#define E_WQKT  8192       // [80][64]  (row 64 = u)
#define E_ZBRT  13312      // [128][128]
#define E_H1T   29696      // [64][192]
#define E_W2T   41984      // [32][64]
#define E_WFT   44032      // [32][64]
#define E_BF16_TOTAL 46080 // floats (192) start at byte 92160

__device__ __forceinline__ unsigned short bfr(float x) {
    unsigned u = __builtin_bit_cast(unsigned, x);
    u += 0x7fffu + ((u >> 16) & 1u);           // round-to-nearest-even
    return (unsigned short)(u >> 16);
}
__device__ __forceinline__ float bf2f(unsigned short h) {
    unsigned u = ((unsigned)h) << 16;
    return __builtin_bit_cast(float, u);
}
__device__ __forceinline__ short8 cvt8v(float4 a, float4 b) {
    short8 r;
    r[0] = (short)bfr(a.x); r[1] = (short)bfr(a.y);
    r[2] = (short)bfr(a.z); r[3] = (short)bfr(a.w);
    r[4] = (short)bfr(b.x); r[5] = (short)bfr(b.y);
    r[6] = (short)bfr(b.z); r[7] = (short)bfr(b.w);
    return r;
}
#define SWZ64(r, c)  ((((r) * 64)  + (c)) ^ (((r) & 7) << 3))
#define SWZ128(r, c) ((((r) * 128) + (c)) ^ (((r) & 7) << 3))
#define SWZ192(r, c) ((((r) * 192) + (c)) ^ (((r) & 7) << 3))

// ---------------------------------------------------------------------------
__global__ __launch_bounds__(256) void qmix_setup(
    const float* __restrict__ ally_w, const float* __restrict__ enemy_w,
    const float* __restrict__ q_w, const float* __restrict__ k_w,
    const float* __restrict__ k_b,
    const float* __restrict__ hw1_w1, const float* __restrict__ hw1_b1,
    const float* __restrict__ hw1_w2,
    const float* __restrict__ hwf_w1, const float* __restrict__ hwf_b1,
    const float* __restrict__ hwf_w2,
    const float* __restrict__ hb1_w, const float* __restrict__ hb1_b,
    const float* __restrict__ v_w1, const float* __restrict__ v_b1,
    const float* __restrict__ tre_w, const float* __restrict__ tre_b,
    unsigned short* __restrict__ wsb, float* __restrict__ wsf)
{
    int gid = blockIdx.x * 256 + threadIdx.x;
    if (gid < E_BF16_TOTAL) {
        float v = 0.f;
        int base, r, c, K;
        if (gid < E_WQKT) {                         // CAT [64][128]
            base = E_CAT; K = 128;
            int i = gid - base; r = i >> 7; c = i & 127;
            v = (c < 64) ? ally_w[c * 64 + r] : enemy_w[(c - 64) * 64 + r];
        } else if (gid < E_ZBRT) {                  // WQKT [80][64]
            base = E_WQKT; K = 64;
            int i = gid - base; r = i >> 6; c = i & 63;
            if (r < 64) {
                for (int g = 0; g < 64; ++g) v += q_w[c * 64 + g] * k_w[r * 64 + g];
            } else if (r == 64) {
                for (int g = 0; g < 64; ++g) v += q_w[c * 64 + g] * k_b[g];
            }
        } else if (gid < E_H1T) {                   // ZBRT [128][128]
            base = E_ZBRT; K = 128;
            int i = gid - base; r = i >> 7; c = i & 127;
            if (r < 64) {
                if (c < 64) v = hwf_w1[c * 64 + r];
                else for (int g = 0; g < 64; ++g) v += tre_w[(c - 64) * 64 + g] * hwf_w1[(64 + g) * 64 + r];
            } else if (r < 96) {
                int m = r - 64;
                if (c < 64) v = hb1_w[c * 32 + m];
                else for (int g = 0; g < 64; ++g) v += tre_w[(c - 64) * 64 + g] * hb1_w[(64 + g) * 32 + m];
            } else {
                int m = r - 96;
                if (c < 64) v = v_w1[c * 32 + m];
                else for (int g = 0; g < 64; ++g) v += tre_w[(c - 64) * 64 + g] * v_w1[(64 + g) * 32 + m];
            }
        } else if (gid < E_W2T) {                   // H1T [64][192]
            base = E_H1T; K = 192;
            int i = gid - base; r = i / 192; c = i % 192;
            if (c < 64) v = hw1_w1[(64 + c) * 64 + r];
            else if (c < 128) {
                for (int g = 0; g < 64; ++g) v += tre_w[(c - 64) * 64 + g] * hw1_w1[(128 + g) * 64 + r];
            } else v = hw1_w1[(c - 128) * 64 + r];
        } else if (gid < E_WFT) {                   // W2T [32][64]
            base = E_W2T; K = 64;
            int i = gid - base; r = i >> 6; c = i & 63;
            v = hw1_w2[c * 32 + r];
        } else {                                    // WFT [32][64]
            base = E_WFT; K = 64;
            int i = gid - base; r = i >> 6; c = i & 63;
            v = hwf_w2[c * 32 + r];
        }
        wsb[base + ((r * K + c) ^ ((r & 7) << 3))] = bfr(v);
    } else if (gid < E_BF16_TOTAL + 192) {
        int j = gid - E_BF16_TOTAL; float v;
        if (j < 64) {
            v = hw1_b1[j];
            for (int g = 0; g < 64; ++g) v += tre_b[g] * hw1_w1[(128 + g) * 64 + j];
        } else if (j < 128) {
            int e = j - 64; v = hwf_b1[e];
            for (int g = 0; g < 64; ++g) v += tre_b[g] * hwf_w1[(64 + g) * 64 + e];
        } else if (j < 160) {
            int m = j - 128; v = hb1_b[m];
            for (int g = 0; g < 64; ++g) v += tre_b[g] * hb1_w[(64 + g) * 32 + m];
        } else {
            int m = j - 160; v = v_b1[m];
            for (int g = 0; g < 64; ++g) v += tre_b[g] * v_w1[(64 + g) * 32 + m];
        }
        wsf[j] = v;
    }
}

// ---------------------------------------------------------------------------
// in-register mean-mu MFMA A-fragment: lane needs mm[tok][f0..f0+7]
__device__ __forceinline__ short8 mmfrag(const float* __restrict__ mp) {
    float a0 = 0.f, a1 = 0.f, a2 = 0.f, a3 = 0.f, a4 = 0.f, a5 = 0.f, a6 = 0.f, a7 = 0.f;
    #pragma unroll
    for (int a = 0; a < 8; ++a) {
        float4 u = *(const float4*)(mp + a * 64);
        float4 v = *(const float4*)(mp + a * 64 + 4);
        a0 += u.x; a1 += u.y; a2 += u.z; a3 += u.w;
        a4 += v.x; a5 += v.y; a6 += v.z; a7 += v.w;
    }
    return cvt8v(make_float4(a0 * 0.125f, a1 * 0.125f, a2 * 0.125f, a3 * 0.125f),
                 make_float4(a4 * 0.125f, a5 * 0.125f, a6 * 0.125f, a7 * 0.125f));
}

// ---------------------------------------------------------------------------
// FUSED kernel: 512 threads = 8 waves, 8 tokens/wave = 64 tokens/block.
__global__ __launch_bounds__(512) void qmix_fused(
    const float* __restrict__ agent_qs, const float* __restrict__ states,
    const float* __restrict__ mu,
    const float* __restrict__ ally_b, const float* __restrict__ enemy_b,
    const float* __restrict__ v_w2, const float* __restrict__ v_b2,
    const float* __restrict__ hw1_b2, const float* __restrict__ hwf_b2,
    const unsigned short* __restrict__ wsb, const float* __restrict__ wsf,
    float* __restrict__ out)
{
    __shared__ unsigned short sW[16384];       // staged weights (A/B/C phases)
    __shared__ unsigned short sE[8][1024];     // ent tile -> z tile -> h1 tile
    __shared__ unsigned short sT[8][1024];     // tmp tile; hyper: [512..767]=b1 bf16, [768..1023]=wf bf16
    __shared__ unsigned short sAO[8][512];     // per-wave ao[8 tok][64] bf16 swz
    __shared__ float sV[8][8];

    const int tid  = threadIdx.x;
    const int lane = tid & 63;
    const int wv   = tid >> 6;
    const int l15  = lane & 15;
    const int lg   = lane >> 4;
    const int kb   = lg * 8;
    const int T0   = blockIdx.x * 64 + wv * 8;     // this wave's first token

    const float* BH1 = wsf + 0;
    const float* BHF = wsf + 64;
    const float* BB1 = wsf + 128;
    const float* BV  = wsf + 160;

    const short8 zero8 = {0, 0, 0, 0, 0, 0, 0, 0};
    const f32x4  zero4 = {0.f, 0.f, 0.f, 0.f};

    unsigned short* E  = sE[wv];
    unsigned short* T  = sT[wv];
    unsigned short* AO = sAO[wv];

    // ========== phase A: stage CAT+WQKT ==========
    for (int i = tid * 8; i < 13312; i += 512 * 8)
        *(short8*)(sW + i) = *(const short8*)(wsb + E_CAT + i);

    float biasEnt[4];
    #pragma unroll
    for (int nt = 0; nt < 4; ++nt) {
        int col = nt * 16 + l15;
        biasEnt[nt] = (lg < 2) ? ally_b[col] : enemy_b[col];
    }
    const int roff = (l15 < 8) ? (l15 * 64 + kb) : (512 + (l15 - 8) * 64 + kb);
    float4 pf[4];
    {
        const float* p = states + (size_t)T0 * 1024 + roff;
        pf[0] = *(const float4*)(p);      pf[1] = *(const float4*)(p + 4);
        pf[2] = *(const float4*)(p + 32); pf[3] = *(const float4*)(p + 36);
    }
    __syncthreads();
    const unsigned short* lCAT  = sW;
    const unsigned short* lWQKT = sW + 8192;

    // ========== attn phase: 8 tokens per wave (r9 chain) ==========
    for (int ti = 0; ti < 8; ++ti) {
        const size_t t = (size_t)(T0 + ti);
        float4 cur0 = pf[0], cur1 = pf[1], cur2 = pf[2], cur3 = pf[3];
        if (ti < 7) {
            const float* p = states + (t + 1) * 1024 + roff;
            pf[0] = *(const float4*)(p);      pf[1] = *(const float4*)(p + 4);
            pf[2] = *(const float4*)(p + 32); pf[3] = *(const float4*)(p + 36);
        }
        short8 a01 = cvt8v(cur0, cur1);
        short8 a23 = cvt8v(cur2, cur3);
        const bool isally = (l15 < 8);

        // B: ent = [ally;enemy] @ CAT (block-diag K=128)
        f32x4 accB[4] = {zero4, zero4, zero4, zero4};
        #pragma unroll
        for (int ks = 0; ks < 4; ++ks) {
            short8 af;
            if (ks == 0)      af = isally ? a01 : zero8;
            else if (ks == 1) af = isally ? a23 : zero8;
            else if (ks == 2) af = isally ? zero8 : a01;
            else              af = isally ? zero8 : a23;
            #pragma unroll
            for (int nt = 0; nt < 4; ++nt) {
                short8 w = *(const short8*)&lCAT[SWZ128(nt * 16 + l15, ks * 32 + kb)];
                accB[nt] = MFMA(af, w, accB[nt]);
            }
        }
        float entv[4][4];
        #pragma unroll
        for (int nt = 0; nt < 4; ++nt) {
            #pragma unroll
            for (int reg = 0; reg < 4; ++reg) {
                entv[nt][reg] = accB[nt][reg] + biasEnt[nt];
                E[SWZ64(lg * 4 + reg, nt * 16 + l15)] = bfr(entv[nt][reg]);
            }
        }

        // C: tmp = ent @ WQKT (N=80; col 64 = si); ef reused for D
        f32x4 accC[5] = {zero4, zero4, zero4, zero4, zero4};
        short8 ef0 = *(const short8*)&E[SWZ64(l15, 0 * 32 + kb)];
        short8 ef1 = *(const short8*)&E[SWZ64(l15, 1 * 32 + kb)];
        #pragma unroll
        for (int nt = 0; nt < 5; ++nt) {
            short8 w0 = *(const short8*)&lWQKT[SWZ64(nt * 16 + l15, 0 * 32 + kb)];
            short8 w1 = *(const short8*)&lWQKT[SWZ64(nt * 16 + l15, 1 * 32 + kb)];
            accC[nt] = MFMA(ef0, w0, accC[nt]);
            accC[nt] = MFMA(ef1, w1, accC[nt]);
        }
        const int src = lane & 48;
        float si[4];
        #pragma unroll
        for (int reg = 0; reg < 4; ++reg) si[reg] = __shfl(accC[4][reg], src);
        #pragma unroll
        for (int nt = 0; nt < 4; ++nt)
            #pragma unroll
            for (int reg = 0; reg < 4; ++reg)
                T[SWZ64(lg * 4 + reg, nt * 16 + l15)] = bfr(accC[nt][reg]);

        // D: energy = tmp @ ent^T (K=64) + si
        f32x4 en = zero4;
        {
            short8 ta0 = *(const short8*)&T[SWZ64(l15, 0 * 32 + kb)];
            short8 ta1 = *(const short8*)&T[SWZ64(l15, 1 * 32 + kb)];
            en = MFMA(ta0, ef0, en);
            en = MFMA(ta1, ef1, en);
        }
        #pragma unroll
        for (int reg = 0; reg < 4; ++reg) en[reg] += si[reg];

        // softmax over i
        float mx = fmaxf(fmaxf(en[0], en[1]), fmaxf(en[2], en[3]));
        mx = fmaxf(mx, __shfl_xor(mx, 16));
        mx = fmaxf(mx, __shfl_xor(mx, 32));
        float p0 = __expf(en[0] - mx), p1 = __expf(en[1] - mx);
        float p2 = __expf(en[2] - mx), p3 = __expf(en[3] - mx);
        float s = p0 + p1 + p2 + p3;
        s += __shfl_xor(s, 16);
        s += __shfl_xor(s, 32);
        float inv = 1.f / s;
        float r0 = p0 * inv, r1 = p1 * inv, r2 = p2 * inv, r3 = p3 * inv;
        r0 += __shfl_xor(r0, 1); r0 += __shfl_xor(r0, 2); r0 += __shfl_xor(r0, 4); r0 += __shfl_xor(r0, 8);
        r1 += __shfl_xor(r1, 1); r1 += __shfl_xor(r1, 2); r1 += __shfl_xor(r1, 4); r1 += __shfl_xor(r1, 8);
        r2 += __shfl_xor(r2, 1); r2 += __shfl_xor(r2, 2); r2 += __shfl_xor(r2, 4); r2 += __shfl_xor(r2, 8);
        r3 += __shfl_xor(r3, 1); r3 += __shfl_xor(r3, 2); r3 += __shfl_xor(r3, 4); r3 += __shfl_xor(r3, 8);

        // ao from registers; write into per-wave sAO row ti
        float part[4];
        #pragma unroll
        for (int nt = 0; nt < 4; ++nt) {
            float pp = r0 * entv[nt][0] + r1 * entv[nt][1]
                     + r2 * entv[nt][2] + r3 * entv[nt][3];
            pp += __shfl_xor(pp, 16);
            pp += __shfl_xor(pp, 32);
            part[nt] = pp;
        }
        float ao = (lg == 0) ? part[0] : (lg == 1) ? part[1]
                 : (lg == 2) ? part[2] : part[3];
        AO[SWZ64(ti, lane)] = bfr(ao * 0.0625f);
    }
    __syncthreads();   // all waves done with CAT/WQKT

    // ========== phase B: stage ZBRT; mm gathers; ao frags ==========
    for (int i = tid * 8; i < 16384; i += 512 * 8)
        *(short8*)(sW + i) = *(const short8*)(wsb + E_ZBRT + i);

    const int arow8 = l15 & 7;
    short8 mm2 = mmfrag(mu + (size_t)(T0 + arow8) * 512 + kb);
    short8 mm3 = mmfrag(mu + (size_t)(T0 + arow8) * 512 + 32 + kb);
    short8 zA0 = *(const short8*)&AO[SWZ64(arow8, kb)];
    short8 zA1 = *(const short8*)&AO[SWZ64(arow8, 32 + kb)];
    __syncthreads();

    // ========== zbr: [8tok x 128] @ ZBRT[128x128] (rows 8-15 idle) ==========
    f32x4 zb[8] = {zero4, zero4, zero4, zero4, zero4, zero4, zero4, zero4};
    const bool arow = (l15 < 8);
    #pragma unroll
    for (int ks = 0; ks < 4; ++ks) {
        short8 af;
        if (ks == 0)      af = arow ? zA0 : zero8;
        else if (ks == 1) af = arow ? zA1 : zero8;
        else if (ks == 2) af = arow ? mm2 : zero8;
        else              af = arow ? mm3 : zero8;
        #pragma unroll
        for (int nt = 0; nt < 8; ++nt) {
            short8 w = *(const short8*)&sW[SWZ128(nt * 16 + l15, ks * 32 + kb)];
            zb[nt] = MFMA(af, w, zb[nt]);
        }
    }
    __syncthreads();   // all waves done reading ZBRT

    // ========== phase C: stage H1T|W2T|WFT; zbr epilogue ==========
    for (int i = tid * 8; i < 16384; i += 512 * 8)
        *(short8*)(sW + i) = *(const short8*)(wsb + E_H1T + i);

    unsigned short* b1T = T + 512;    // [8 tok][32] bf16 (tmp tile dead)
    unsigned short* wfT = T + 768;    // [8 tok][32] bf16
    // zero z rows 8-15 of E (read by wf A-frags, never written)
    for (int i = lane; i < 512; i += 64) E[512 + i] = 0;
    if (lg < 2) {
        #pragma unroll
        for (int nt = 0; nt < 4; ++nt) {          // z = relu(...)
            int col = nt * 16 + l15;
            float bz = BHF[col];
            #pragma unroll
            for (int reg = 0; reg < 4; ++reg)
                E[SWZ64(lg * 4 + reg, col)] = bfr(fmaxf(zb[nt][reg] + bz, 0.f));
        }
        #pragma unroll
        for (int nt = 4; nt < 6; ++nt) {          // b1 (bf16)
            int m = (nt - 4) * 16 + l15;
            float bb = BB1[m];
            #pragma unroll
            for (int reg = 0; reg < 4; ++reg)
                b1T[(lg * 4 + reg) * 32 + m] = bfr(zb[nt][reg] + bb);
        }
    }
    {                                              // rv -> v scalar per token
        float bv0 = BV[l15], bv1 = BV[16 + l15];
        float vw0 = v_w2[l15], vw1 = v_w2[16 + l15];
        #pragma unroll
        for (int reg = 0; reg < 4; ++reg) {
            float vp = fmaxf(zb[6][reg] + bv0, 0.f) * vw0
                     + fmaxf(zb[7][reg] + bv1, 0.f) * vw1;
            vp += __shfl_xor(vp, 1); vp += __shfl_xor(vp, 2);
            vp += __shfl_xor(vp, 4); vp += __shfl_xor(vp, 8);
            if (l15 == 0 && lg < 2) sV[wv][lg * 4 + reg] = vp;
        }
    }
    // prefetch first h1 chunk while H1T staging drains
    const int agent = l15 & 7;
    const int toff  = l15 >> 3;
    float4 cs0, cs1, cs2, cs3, cm0, cm1, cm2, cm3;
    {
        const size_t tokA = (size_t)(T0 + toff);
        const float* sp = states + tokA * 1024 + agent * 64 + kb;
        const float* mp = mu + tokA * 512 + agent * 64 + kb;
        cs0 = *(const float4*)sp;        cs1 = *(const float4*)(sp + 4);
        cs2 = *(const float4*)(sp + 32); cs3 = *(const float4*)(sp + 36);
        cm0 = *(const float4*)mp;        cm1 = *(const float4*)(mp + 4);
        cm2 = *(const float4*)(mp + 32); cm3 = *(const float4*)(mp + 36);
    }
    __syncthreads();
    const unsigned short* lH1T = sW;
    const unsigned short* lW2T = sW + 12288;
    const unsigned short* lWFT = sW + 14336;

    // ========== wf = |relu(z) @ WFT + b2| (rows 8-15 zero) ==========
    {
        f32x4 wfa = zero4, wfb = zero4;
        #pragma unroll
        for (int ks = 0; ks < 2; ++ks) {
            short8 af = *(const short8*)&E[SWZ64(l15, ks * 32 + kb)];
            short8 b0 = *(const short8*)&lWFT[SWZ64(l15, ks * 32 + kb)];
            short8 b1 = *(const short8*)&lWFT[SWZ64(16 + l15, ks * 32 + kb)];
            wfa = MFMA(af, b0, wfa);
            wfb = MFMA(af, b1, wfb);
        }
        if (lg < 2) {
            float hb0 = hwf_b2[l15], hb1 = hwf_b2[16 + l15];
            #pragma unroll
            for (int reg = 0; reg < 4; ++reg) {
                int tok = lg * 4 + reg;
                wfT[tok * 32 + l15]      = bfr(fabsf(wfa[reg] + hb0));
                wfT[tok * 32 + 16 + l15] = bfr(fabsf(wfb[reg] + hb1));
            }
        }
    }

    // ====== h1/w1: 4 mini-chunks of 2 tokens (tile in E; ao from sAO) ======
    const float vb2 = v_b2[0];
    const float b20 = hw1_b2[l15], b21 = hw1_b2[16 + l15];

    for (int mc = 0; mc < 4; ++mc) {
        float4 us0 = cs0, us1 = cs1, us2 = cs2, us3 = cs3;
        float4 um0 = cm0, um1 = cm1, um2 = cm2, um3 = cm3;
        if (mc < 3) {                          // prefetch next mini-chunk
            const size_t tokA = (size_t)(T0 + (mc + 1) * 2 + toff);
            const float* sp = states + tokA * 1024 + agent * 64 + kb;
            const float* mp = mu + tokA * 512 + agent * 64 + kb;
            cs0 = *(const float4*)sp;        cs1 = *(const float4*)(sp + 4);
            cs2 = *(const float4*)(sp + 32); cs3 = *(const float4*)(sp + 36);
            cm0 = *(const float4*)mp;        cm1 = *(const float4*)(mp + 4);
            cm2 = *(const float4*)(mp + 32); cm3 = *(const float4*)(mp + 36);
        }
        short8 f0 = cvt8v(us0, us1), f1 = cvt8v(us2, us3);
        short8 f2 = cvt8v(um0, um1), f3 = cvt8v(um2, um3);
        short8 ua0 = *(const short8*)&AO[SWZ64(mc * 2 + toff, kb)];
        short8 ua1 = *(const short8*)&AO[SWZ64(mc * 2 + toff, 32 + kb)];

        // h1 = relu([ally | mu | ao] @ H1T + BH1), rows = 2 tok x 8 agents
        f32x4 h[4] = {zero4, zero4, zero4, zero4};
        #pragma unroll
        for (int ks = 0; ks < 6; ++ks) {
            short8 af = (ks == 0) ? f0 : (ks == 1) ? f1 : (ks == 2) ? f2
                      : (ks == 3) ? f3 : (ks == 4) ? ua0 : ua1;
            #pragma unroll
            for (int nt = 0; nt < 4; ++nt) {
                short8 w = *(const short8*)&lH1T[SWZ192(nt * 16 + l15, ks * 32 + kb)];
                h[nt] = MFMA(af, w, h[nt]);
            }
        }
        #pragma unroll
        for (int nt = 0; nt < 4; ++nt) {
            int col = nt * 16 + l15;
            float bh = BH1[col];
            #pragma unroll
            for (int reg = 0; reg < 4; ++reg)
                E[SWZ64(lg * 4 + reg, col)] = bfr(fmaxf(h[nt][reg] + bh, 0.f));
        }

        // w1 = |h1 @ W2T + b2|
        f32x4 wa = zero4, wb = zero4;
        #pragma unroll
        for (int ks = 0; ks < 2; ++ks) {
            short8 af = *(const short8*)&E[SWZ64(l15, ks * 32 + kb)];
            short8 b0 = *(const short8*)&lW2T[SWZ64(l15, ks * 32 + kb)];
            short8 b1 = *(const short8*)&lW2T[SWZ64(16 + l15, ks * 32 + kb)];
            wa = MFMA(af, b0, wa);
            wb = MFMA(af, b1, wb);
        }

        // hidden = elu(sum_a qs*|w1| + b1); q = sum_m hidden*wf + v
        float hp0 = 0.f, hp1 = 0.f;
        #pragma unroll
        for (int reg = 0; reg < 4; ++reg) {
            int row = lg * 4 + reg;
            float qsv = agent_qs[(size_t)(T0 + mc * 2 + (row >> 3)) * 8 + (row & 7)];
            hp0 += qsv * fabsf(wa[reg] + b20);
            hp1 += qsv * fabsf(wb[reg] + b21);
        }
        hp0 += __shfl_xor(hp0, 16);       // sum the 8 agents of own token
        hp1 += __shfl_xor(hp1, 16);
        int tokL = mc * 2 + (lg >> 1);
        float e0 = hp0 + bf2f(b1T[tokL * 32 + l15]);
        float e1 = hp1 + bf2f(b1T[tokL * 32 + 16 + l15]);
        float hid0 = e0 > 0.f ? e0 : (__expf(e0) - 1.f);
        float hid1 = e1 > 0.f ? e1 : (__expf(e1) - 1.f);
        float q = hid0 * bf2f(wfT[tokL * 32 + l15])
                + hid1 * bf2f(wfT[tokL * 32 + 16 + l15]);
        q += __shfl_xor(q, 1); q += __shfl_xor(q, 2);
        q += __shfl_xor(q, 4); q += __shfl_xor(q, 8);
        if (l15 == 0 && (lg & 1) == 0)
            out[T0 + tokL] = q + sV[wv][tokL] + vb2;
    }
}

// ---------------------------------------------------------------------------
extern "C" void kernel_launch(void* const* d_in, const int* in_sizes, int n_in,
                              void* d_out, int out_size, void* d_ws, size_t ws_size,
                              hipStream_t stream)
{
    const float* agent_qs = (const float*)d_in[0];
    const float* states   = (const float*)d_in[1];
    const float* mu       = (const float*)d_in[2];
    const float* ally_w   = (const float*)d_in[3];
    const float* ally_b   = (const float*)d_in[4];
    const float* enemy_w  = (const float*)d_in[5];
    const float* enemy_b  = (const float*)d_in[6];
    const float* q_w      = (const float*)d_in[7];
    // d_in[8] = q_b: cancels in softmax over query axis
    const float* k_w      = (const float*)d_in[9];
    const float* k_b      = (const float*)d_in[10];
    const float* hw1_w1   = (const float*)d_in[11];
    const float* hw1_b1   = (const float*)d_in[12];
    const float* hw1_w2   = (const float*)d_in[13];
    const float* hw1_b2   = (const float*)d_in[14];
    const float* hwf_w1   = (const float*)d_in[15];
    const float* hwf_b1   = (const float*)d_in[16];
    const float* hwf_w2   = (const float*)d_in[17];
    const float* hwf_b2   = (const float*)d_in[18];
    const float* hb1_w    = (const float*)d_in[19];
    const float* hb1_b    = (const float*)d_in[20];
    const float* v_w1     = (const float*)d_in[21];
    const float* v_b1     = (const float*)d_in[22];
    const float* v_w2     = (const float*)d_in[23];
    const float* v_b2     = (const float*)d_in[24];
    const float* tre_w    = (const float*)d_in[25];
    const float* tre_b    = (const float*)d_in[26];

    unsigned short* wsb = (unsigned short*)d_ws;
    float* wsf = (float*)((char*)d_ws + (size_t)E_BF16_TOTAL * 2);
    float* out = (float*)d_out;

    hipLaunchKernelGGL(qmix_setup, dim3(181), dim3(256), 0, stream,
                       ally_w, enemy_w, q_w, k_w, k_b,
                       hw1_w1, hw1_b1, hw1_w2,
                       hwf_w1, hwf_b1, hwf_w2,
                       hb1_w, hb1_b, v_w1, v_b1, tre_w, tre_b,
                       wsb, wsf);

    hipLaunchKernelGGL(qmix_fused, dim3(TOKS / 64), dim3(512), 0, stream,
                       agent_qs, states, mu, ally_b, enemy_b,
                       v_w2, v_b2, hw1_b2, hwf_b2,
                       wsb, wsf, out);
}

// Round 15
// 87.425 us; speedup vs baseline: 1.1255x; 1.1255x over previous
//
#include <hip/hip_runtime.h>
#include <math.h>

// ---------------------------------------------------------------------------
// QMixer forward, round 15: r13 (best, 88.7us) + shortened attn epilogue.
// r14 fusion REGRESSED (120us fused vs 73us split despite -80MB traffic);
// reverted. Chain audit: attn softmax epilogue = 28 serial shuffles (~1.1K of
// ~1.45Kcy/token chain); VGPR=128 caps hiding at 4 waves/SIMD -> shorten it:
// rowsum 16 shfls -> LDS-transpose reduce in the dead tmp tile (4 ds_write
// pad-20 + 4 ds_read_b128 + 15 adds + 4 redistribute shfls). Epilogue 28->16
// shuffles. Wave-private tile, in-order DS pipe, no barrier.
// hyper/setup identical to r13.
// ---------------------------------------------------------------------------

#define TOKS 32768

typedef __attribute__((ext_vector_type(8))) short short8;
typedef __attribute__((ext_vector_type(4))) float f32x4;

#define MFMA(a, b, c) __builtin_amdgcn_mfma_f32_16x16x32_bf16((a), (b), (c), 0, 0, 0)

// ws element offsets (ushort units for bf16 part) -- all regions SWIZZLED
#define E_CAT   0          // [64][128]
#define E_WQKT  8192       // [80][64]  (row 64 = u)
#define E_ZBRT  13312      // [128][128]
#define E_H1T   29696      // [64][192]
#define E_W2T   41984      // [32][64]
#define E_WFT   44032      // [32][64]
#define E_BF16_TOTAL 46080 // floats (192) start at byte 92160
#define E_AO_US 46464      // ao[32768][64] bf16

__device__ __forceinline__ unsigned short bfr(float x) {
    unsigned u = __builtin_bit_cast(unsigned, x);
    u += 0x7fffu + ((u >> 16) & 1u);           // round-to-nearest-even
    return (unsigned short)(u >> 16);
}
__device__ __forceinline__ float bf2f(unsigned short h) {
    unsigned u = ((unsigned)h) << 16;
    return __builtin_bit_cast(float, u);
}
__device__ __forceinline__ short8 cvt8v(float4 a, float4 b) {
    short8 r;
    r[0] = (short)bfr(a.x); r[1] = (short)bfr(a.y);
    r[2] = (short)bfr(a.z); r[3] = (short)bfr(a.w);
    r[4] = (short)bfr(b.x); r[5] = (short)bfr(b.y);
    r[6] = (short)bfr(b.z); r[7] = (short)bfr(b.w);
    return r;
}
#define SWZ64(r, c)  ((((r) * 64)  + (c)) ^ (((r) & 7) << 3))
#define SWZ128(r, c) ((((r) * 128) + (c)) ^ (((r) & 7) << 3))
#define SWZ192(r, c) ((((r) * 192) + (c)) ^ (((r) & 7) << 3))

// ---------------------------------------------------------------------------
__global__ __launch_bounds__(256) void qmix_setup(
    const float* __restrict__ ally_w, const float* __restrict__ enemy_w,
    const float* __restrict__ q_w, const float* __restrict__ k_w,
    const float* __restrict__ k_b,
    const float* __restrict__ hw1_w1, const float* __restrict__ hw1_b1,
    const float* __restrict__ hw1_w2,
    const float* __restrict__ hwf_w1, const float* __restrict__ hwf_b1,
    const float* __restrict__ hwf_w2,
    const float* __restrict__ hb1_w, const float* __restrict__ hb1_b,
    const float* __restrict__ v_w1, const float* __restrict__ v_b1,
    const float* __restrict__ tre_w, const float* __restrict__ tre_b,
    unsigned short* __restrict__ wsb, float* __restrict__ wsf)
{
    int gid = blockIdx.x * 256 + threadIdx.x;
    if (gid < E_BF16_TOTAL) {
        float v = 0.f;
        int base, r, c, K;
        if (gid < E_WQKT) {                         // CAT [64][128]
            base = E_CAT; K = 128;
            int i = gid - base; r = i >> 7; c = i & 127;
            v = (c < 64) ? ally_w[c * 64 + r] : enemy_w[(c - 64) * 64 + r];
        } else if (gid < E_ZBRT) {                  // WQKT [80][64]
            base = E_WQKT; K = 64;
            int i = gid - base; r = i >> 6; c = i & 63;
            if (r < 64) {
                for (int g = 0; g < 64; ++g) v += q_w[c * 64 + g] * k_w[r * 64 + g];
            } else if (r == 64) {
                for (int g = 0; g < 64; ++g) v += q_w[c * 64 + g] * k_b[g];
            }
        } else if (gid < E_H1T) {                   // ZBRT [128][128]
            base = E_ZBRT; K = 128;
            int i = gid - base; r = i >> 7; c = i & 127;
            if (r < 64) {
                if (c < 64) v = hwf_w1[c * 64 + r];
                else for (int g = 0; g < 64; ++g) v += tre_w[(c - 64) * 64 + g] * hwf_w1[(64 + g) * 64 + r];
            } else if (r < 96) {
                int m = r - 64;
                if (c < 64) v = hb1_w[c * 32 + m];
                else for (int g = 0; g < 64; ++g) v += tre_w[(c - 64) * 64 + g] * hb1_w[(64 + g) * 32 + m];
            } else {
                int m = r - 96;
                if (c < 64) v = v_w1[c * 32 + m];
                else for (int g = 0; g < 64; ++g) v += tre_w[(c - 64) * 64 + g] * v_w1[(64 + g) * 32 + m];
            }
        } else if (gid < E_W2T) {                   // H1T [64][192]
            base = E_H1T; K = 192;
            int i = gid - base; r = i / 192; c = i % 192;
            if (c < 64) v = hw1_w1[(64 + c) * 64 + r];
            else if (c < 128) {
                for (int g = 0; g < 64; ++g) v += tre_w[(c - 64) * 64 + g] * hw1_w1[(128 + g) * 64 + r];
            } else v = hw1_w1[(c - 128) * 64 + r];
        } else if (gid < E_WFT) {                   // W2T [32][64]
            base = E_W2T; K = 64;
            int i = gid - base; r = i >> 6; c = i & 63;
            v = hw1_w2[c * 32 + r];
        } else {                                    // WFT [32][64]
            base = E_WFT; K = 64;
            int i = gid - base; r = i >> 6; c = i & 63;
            v = hwf_w2[c * 32 + r];
        }
        wsb[base + ((r * K + c) ^ ((r & 7) << 3))] = bfr(v);
    } else if (gid < E_BF16_TOTAL + 192) {
        int j = gid - E_BF16_TOTAL; float v;
        if (j < 64) {
            v = hw1_b1[j];
            for (int g = 0; g < 64; ++g) v += tre_b[g] * hw1_w1[(128 + g) * 64 + j];
        } else if (j < 128) {
            int e = j - 64; v = hwf_b1[e];
            for (int g = 0; g < 64; ++g) v += tre_b[g] * hwf_w1[(64 + g) * 64 + e];
        } else if (j < 160) {
            int m = j - 128; v = hb1_b[m];
            for (int g = 0; g < 64; ++g) v += tre_b[g] * hb1_w[(64 + g) * 32 + m];
        } else {
            int m = j - 160; v = v_b1[m];
            for (int g = 0; g < 64; ++g) v += tre_b[g] * v_w1[(64 + g) * 32 + m];
        }
        wsf[j] = v;
    }
}

// ---------------------------------------------------------------------------
// Kernel A: attention. 512 threads, ONE token per wave. LDS-transpose rowsum.
__global__ __launch_bounds__(512) void qmix_attn(
    const float* __restrict__ states,
    const float* __restrict__ ally_b, const float* __restrict__ enemy_b,
    const unsigned short* __restrict__ wsb,
    unsigned short* __restrict__ aoG)
{
    __shared__ unsigned short sWa[13312];      // CAT 8192 + WQKT 5120 (26KB)
    __shared__ unsigned short sE[8][1024];
    __shared__ unsigned short sT[8][1024];     // tmp tile; PW overlay after D

    const int lane = threadIdx.x & 63;
    const int wv   = threadIdx.x >> 6;
    const int l15  = lane & 15;
    const int lg   = lane >> 4;
    const int kb   = lg * 8;
    const size_t t = (size_t)blockIdx.x * 8 + wv;

    const short8 zero8 = {0, 0, 0, 0, 0, 0, 0, 0};
    const f32x4  zero4 = {0.f, 0.f, 0.f, 0.f};

    for (int i = threadIdx.x * 8; i < 13312; i += 512 * 8)
        *(short8*)(sWa + i) = *(const short8*)(wsb + E_CAT + i);

    const int roff = (l15 < 8) ? (l15 * 64 + kb) : (512 + (l15 - 8) * 64 + kb);
    const float* p = states + t * 1024 + roff;
    float4 cur0 = *(const float4*)(p);
    float4 cur1 = *(const float4*)(p + 4);
    float4 cur2 = *(const float4*)(p + 32);
    float4 cur3 = *(const float4*)(p + 36);

    float biasEnt[4];
    #pragma unroll
    for (int nt = 0; nt < 4; ++nt) {
        int col = nt * 16 + l15;
        biasEnt[nt] = (lg < 2) ? ally_b[col] : enemy_b[col];
    }
    __syncthreads();
    const unsigned short* lCAT  = sWa;
    const unsigned short* lWQKT = sWa + 8192;

    unsigned short* E = sE[wv];
    unsigned short* T = sT[wv];

    short8 a01 = cvt8v(cur0, cur1);
    short8 a23 = cvt8v(cur2, cur3);
    const bool isally = (l15 < 8);

    // ---- B: ent = [ally;enemy] @ CAT (block-diag K=128) ----
    f32x4 accB[4] = {zero4, zero4, zero4, zero4};
    #pragma unroll
    for (int ks = 0; ks < 4; ++ks) {
        short8 af;
        if (ks == 0)      af = isally ? a01 : zero8;
        else if (ks == 1) af = isally ? a23 : zero8;
        else if (ks == 2) af = isally ? zero8 : a01;
        else              af = isally ? zero8 : a23;
        #pragma unroll
        for (int nt = 0; nt < 4; ++nt) {
            short8 w = *(const short8*)&lCAT[SWZ128(nt * 16 + l15, ks * 32 + kb)];
            accB[nt] = MFMA(af, w, accB[nt]);
        }
    }
    float entv[4][4];
    #pragma unroll
    for (int nt = 0; nt < 4; ++nt) {
        #pragma unroll
        for (int reg = 0; reg < 4; ++reg) {
            entv[nt][reg] = accB[nt][reg] + biasEnt[nt];
            E[SWZ64(lg * 4 + reg, nt * 16 + l15)] = bfr(entv[nt][reg]);
        }
    }

    // ---- C: tmp = ent @ WQKT (N=80; col 64 = si); ef reused for D ----
    f32x4 accC[5] = {zero4, zero4, zero4, zero4, zero4};
    short8 ef0 = *(const short8*)&E[SWZ64(l15, 0 * 32 + kb)];
    short8 ef1 = *(const short8*)&E[SWZ64(l15, 1 * 32 + kb)];
    #pragma unroll
    for (int nt = 0; nt < 5; ++nt) {
        short8 w0 = *(const short8*)&lWQKT[SWZ64(nt * 16 + l15, 0 * 32 + kb)];
        short8 w1 = *(const short8*)&lWQKT[SWZ64(nt * 16 + l15, 1 * 32 + kb)];
        accC[nt] = MFMA(ef0, w0, accC[nt]);
        accC[nt] = MFMA(ef1, w1, accC[nt]);
    }
    const int src = lane & 48;
    float si[4];
    #pragma unroll
    for (int reg = 0; reg < 4; ++reg) si[reg] = __shfl(accC[4][reg], src);
    #pragma unroll
    for (int nt = 0; nt < 4; ++nt)
        #pragma unroll
        for (int reg = 0; reg < 4; ++reg)
            T[SWZ64(lg * 4 + reg, nt * 16 + l15)] = bfr(accC[nt][reg]);

    // ---- D: energy = tmp @ ent^T (K=64) + si ----
    f32x4 en = zero4;
    {
        short8 ta0 = *(const short8*)&T[SWZ64(l15, 0 * 32 + kb)];
        short8 ta1 = *(const short8*)&T[SWZ64(l15, 1 * 32 + kb)];
        en = MFMA(ta0, ef0, en);
        en = MFMA(ta1, ef1, en);
    }
    #pragma unroll
    for (int reg = 0; reg < 4; ++reg) en[reg] += si[reg];

    // ---- softmax over i (rows i = lg*4+reg; col j = l15) ----
    float mx = fmaxf(fmaxf(en[0], en[1]), fmaxf(en[2], en[3]));
    mx = fmaxf(mx, __shfl_xor(mx, 16));
    mx = fmaxf(mx, __shfl_xor(mx, 32));
    float p0 = __expf(en[0] - mx), p1 = __expf(en[1] - mx);
    float p2 = __expf(en[2] - mx), p3 = __expf(en[3] - mx);
    float s = p0 + p1 + p2 + p3;
    s += __shfl_xor(s, 16);
    s += __shfl_xor(s, 32);
    float inv = 1.f / s;
    float r0 = p0 * inv, r1 = p1 * inv, r2 = p2 * inv, r3 = p3 * inv;

    // ---- rowsum over j via LDS transpose (replaces 16 shuffles) ----
    // tmp tile dead after D; reuse as fp32 [16][20] (pad 20: b128-aligned rows,
    // write conflicts <=2-way which is free per G4).
    float* PW = (float*)T;
    PW[(lg * 4 + 0) * 20 + l15] = r0;
    PW[(lg * 4 + 1) * 20 + l15] = r1;
    PW[(lg * 4 + 2) * 20 + l15] = r2;
    PW[(lg * 4 + 3) * 20 + l15] = r3;
    // wave-private + in-order DS pipe: reads below get the new data
    float4 q0 = *(const float4*)&PW[l15 * 20 + 0];
    float4 q1 = *(const float4*)&PW[l15 * 20 + 4];
    float4 q2 = *(const float4*)&PW[l15 * 20 + 8];
    float4 q3 = *(const float4*)&PW[l15 * 20 + 12];
    float rs_own = ((q0.x + q0.y) + (q0.z + q0.w)) + ((q1.x + q1.y) + (q1.z + q1.w))
                 + ((q2.x + q2.y) + (q2.z + q2.w)) + ((q3.x + q3.y) + (q3.z + q3.w));
    // redistribute: lane needs rs[lg*4+reg] (source lane in same 16-group)
    float rr[4];
    #pragma unroll
    for (int reg = 0; reg < 4; ++reg)
        rr[reg] = __shfl(rs_own, (lane & 48) | (lg * 4 + reg));

    // ---- ao from registers: ao[e] = (1/16) sum_n rs[n]*ent[n][e] ----
    float part[4];
    #pragma unroll
    for (int nt = 0; nt < 4; ++nt) {
        float pp = rr[0] * entv[nt][0] + rr[1] * entv[nt][1]
                 + rr[2] * entv[nt][2] + rr[3] * entv[nt][3];
        pp += __shfl_xor(pp, 16);
        pp += __shfl_xor(pp, 32);
        part[nt] = pp;
    }
    float ao = (lg == 0) ? part[0] : (lg == 1) ? part[1]
             : (lg == 2) ? part[2] : part[3];
    aoG[t * 64 + lane] = bfr(ao * 0.0625f);
}

// ---------------------------------------------------------------------------
__device__ __forceinline__ short8 mmfrag(const float* __restrict__ mp) {
    float a0 = 0.f, a1 = 0.f, a2 = 0.f, a3 = 0.f, a4 = 0.f, a5 = 0.f, a6 = 0.f, a7 = 0.f;
    #pragma unroll
    for (int a = 0; a < 8; ++a) {
        float4 u = *(const float4*)(mp + a * 64);
        float4 v = *(const float4*)(mp + a * 64 + 4);
        a0 += u.x; a1 += u.y; a2 += u.z; a3 += u.w;
        a4 += v.x; a5 += v.y; a6 += v.z; a7 += v.w;
    }
    return cvt8v(make_float4(a0 * 0.125f, a1 * 0.125f, a2 * 0.125f, a3 * 0.125f),
                 make_float4(a4 * 0.125f, a5 * 0.125f, a6 * 0.125f, a7 * 0.125f));
}

// Kernel B: hypernet (r13). 512 threads = 8 waves, 8 tokens/wave, grid 512.
__global__ __launch_bounds__(512) void qmix_hyper(
    const float* __restrict__ agent_qs, const float* __restrict__ states,
    const float* __restrict__ mu,
    const float* __restrict__ v_w2, const float* __restrict__ v_b2,
    const float* __restrict__ hw1_b2, const float* __restrict__ hwf_b2,
    const unsigned short* __restrict__ wsb, const float* __restrict__ wsf,
    const unsigned short* __restrict__ aoG,
    float* __restrict__ out)
{
    __shared__ unsigned short sWb[16384];      // 32KB: ZBRT, then H1T|W2T|WFT
    __shared__ unsigned short sMM[8192];       // [64][64] mean-mu bf16
    __shared__ unsigned short sZT[8][1024];    // per-wave: z [16][64]; h1 tile later
    __shared__ float sB1[8][256];
    __shared__ float sWF[8][256];
    __shared__ float sV[8][8];

    const int tid  = threadIdx.x;
    const int lane = tid & 63;
    const int wv   = tid >> 6;
    const int l15  = lane & 15;
    const int lg   = lane >> 4;
    const int kb   = lg * 8;
    const int T0   = blockIdx.x * 64 + wv * 8;
    const int tokB = blockIdx.x * 64;

    const float* BH1 = wsf + 0;
    const float* BHF = wsf + 64;
    const float* BB1 = wsf + 128;
    const float* BV  = wsf + 160;

    const short8 zero8 = {0, 0, 0, 0, 0, 0, 0, 0};
    const f32x4  zero4 = {0.f, 0.f, 0.f, 0.f};

    for (int i = tid * 8; i < 16384; i += 512 * 8)
        *(short8*)(sWb + i) = *(const short8*)(wsb + E_ZBRT + i);

    short8 zA0 = *(const short8*)&aoG[(size_t)(T0 + (l15 & 7)) * 64 + kb];
    short8 zA1 = *(const short8*)&aoG[(size_t)(T0 + (l15 & 7)) * 64 + 32 + kb];

    // block-cooperative mean-mu -> sMM (coalesced)
    {
        int tok = tid >> 3;
        int e8  = (tid & 7) * 8;
        const float* mp = mu + (size_t)(tokB + tok) * 512 + e8;
        float s0 = 0.f, s1 = 0.f, s2 = 0.f, s3 = 0.f,
              s4 = 0.f, s5 = 0.f, s6 = 0.f, s7 = 0.f;
        #pragma unroll
        for (int a = 0; a < 8; ++a) {
            float4 u = *(const float4*)(mp + a * 64);
            float4 v = *(const float4*)(mp + a * 64 + 4);
            s0 += u.x; s1 += u.y; s2 += u.z; s3 += u.w;
            s4 += v.x; s5 += v.y; s6 += v.z; s7 += v.w;
        }
        short8 r;
        r[0] = (short)bfr(s0 * 0.125f); r[1] = (short)bfr(s1 * 0.125f);
        r[2] = (short)bfr(s2 * 0.125f); r[3] = (short)bfr(s3 * 0.125f);
        r[4] = (short)bfr(s4 * 0.125f); r[5] = (short)bfr(s5 * 0.125f);
        r[6] = (short)bfr(s6 * 0.125f); r[7] = (short)bfr(s7 * 0.125f);
        *(short8*)&sMM[SWZ64(tok, e8)] = r;
    }
    for (int i = lane; i < 512; i += 64) sZT[wv][512 + i] = 0;
    __syncthreads();

    // zbr: [8tok x 128] @ ZBRT[128x128] (rows 8-15 idle)
    f32x4 zb[8] = {zero4, zero4, zero4, zero4, zero4, zero4, zero4, zero4};
    const bool arow = (l15 < 8);
    #pragma unroll
    for (int ks = 0; ks < 4; ++ks) {
        short8 af;
        if (ks == 0)      af = arow ? zA0 : zero8;
        else if (ks == 1) af = arow ? zA1 : zero8;
        else {
            short8 m = *(const short8*)&sMM[SWZ64(wv * 8 + (l15 & 7), (ks - 2) * 32 + kb)];
            af = arow ? m : zero8;
        }
        #pragma unroll
        for (int nt = 0; nt < 8; ++nt) {
            short8 w = *(const short8*)&sWb[SWZ128(nt * 16 + l15, ks * 32 + kb)];
            zb[nt] = MFMA(af, w, zb[nt]);
        }
    }
    __syncthreads();

    for (int i = tid * 8; i < 16384; i += 512 * 8)
        *(short8*)(sWb + i) = *(const short8*)(wsb + E_H1T + i);

    if (lg < 2) {
        #pragma unroll
        for (int nt = 0; nt < 4; ++nt) {          // z = relu(...)
            int col = nt * 16 + l15;
            float bz = BHF[col];
            #pragma unroll
            for (int reg = 0; reg < 4; ++reg)
                sZT[wv][SWZ64(lg * 4 + reg, col)] = bfr(fmaxf(zb[nt][reg] + bz, 0.f));
        }
        #pragma unroll
        for (int nt = 4; nt < 6; ++nt) {          // b1
            int m = (nt - 4) * 16 + l15;
            float bb = BB1[m];
            #pragma unroll
            for (int reg = 0; reg < 4; ++reg)
                sB1[wv][(lg * 4 + reg) * 32 + m] = zb[nt][reg] + bb;
        }
    }
    {                                              // rv -> v scalar per token
        float bv0 = BV[l15], bv1 = BV[16 + l15];
        float vw0 = v_w2[l15], vw1 = v_w2[16 + l15];
        #pragma unroll
        for (int reg = 0; reg < 4; ++reg) {
            float vp = fmaxf(zb[6][reg] + bv0, 0.f) * vw0
                     + fmaxf(zb[7][reg] + bv1, 0.f) * vw1;
            vp += __shfl_xor(vp, 1); vp += __shfl_xor(vp, 2);
            vp += __shfl_xor(vp, 4); vp += __shfl_xor(vp, 8);
            if (l15 == 0 && lg < 2) sV[wv][lg * 4 + reg] = vp;
        }
    }
    __syncthreads();
    const unsigned short* lH1T = sWb;
    const unsigned short* lW2T = sWb + 12288;
    const unsigned short* lWFT = sWb + 14336;

    // wf = |relu(z) @ WFT + b2| (rows 8-15 zero)
    {
        f32x4 wfa = zero4, wfb = zero4;
        #pragma unroll
        for (int ks = 0; ks < 2; ++ks) {
            short8 af = *(const short8*)&sZT[wv][SWZ64(l15, ks * 32 + kb)];
            short8 b0 = *(const short8*)&lWFT[SWZ64(l15, ks * 32 + kb)];
            short8 b1 = *(const short8*)&lWFT[SWZ64(16 + l15, ks * 32 + kb)];
            wfa = MFMA(af, b0, wfa);
            wfb = MFMA(af, b1, wfb);
        }
        if (lg < 2) {
            float hb0 = hwf_b2[l15], hb1 = hwf_b2[16 + l15];
            #pragma unroll
            for (int reg = 0; reg < 4; ++reg) {
                int tok = lg * 4 + reg;
                sWF[wv][tok * 32 + l15]      = fabsf(wfa[reg] + hb0);
                sWF[wv][tok * 32 + 16 + l15] = fabsf(wfb[reg] + hb1);
            }
        }
    }

    // h1/w1: 4 mini-chunks of 2 tokens, double-buffered A prefetch
    const float vb2 = v_b2[0];
    const float b20 = hw1_b2[l15], b21 = hw1_b2[16 + l15];
    const int agent = l15 & 7;
    const int toff  = l15 >> 3;
    unsigned short* tile = sZT[wv];           // overlay (z dead after wf)

    float4 cs0, cs1, cs2, cs3, cm0, cm1, cm2, cm3;
    short8 ca0, ca1;
    {
        const size_t tokA = (size_t)(T0 + toff);
        const float* sp = states + tokA * 1024 + agent * 64 + kb;
        const float* mp = mu + tokA * 512 + agent * 64 + kb;
        cs0 = *(const float4*)sp;        cs1 = *(const float4*)(sp + 4);
        cs2 = *(const float4*)(sp + 32); cs3 = *(const float4*)(sp + 36);
        cm0 = *(const float4*)mp;        cm1 = *(const float4*)(mp + 4);
        cm2 = *(const float4*)(mp + 32); cm3 = *(const float4*)(mp + 36);
        ca0 = *(const short8*)&aoG[tokA * 64 + kb];
        ca1 = *(const short8*)&aoG[tokA * 64 + 32 + kb];
    }

    for (int mc = 0; mc < 4; ++mc) {
        float4 us0 = cs0, us1 = cs1, us2 = cs2, us3 = cs3;
        float4 um0 = cm0, um1 = cm1, um2 = cm2, um3 = cm3;
        short8 ua0 = ca0, ua1 = ca1;
        if (mc < 3) {                          // prefetch next mini-chunk
            const size_t tokA = (size_t)(T0 + (mc + 1) * 2 + toff);
            const float* sp = states + tokA * 1024 + agent * 64 + kb;
            const float* mp = mu + tokA * 512 + agent * 64 + kb;
            cs0 = *(const float4*)sp;        cs1 = *(const float4*)(sp + 4);
            cs2 = *(const float4*)(sp + 32); cs3 = *(const float4*)(sp + 36);
            cm0 = *(const float4*)mp;        cm1 = *(const float4*)(mp + 4);
            cm2 = *(const float4*)(mp + 32); cm3 = *(const float4*)(mp + 36);
            ca0 = *(const short8*)&aoG[tokA * 64 + kb];
            ca1 = *(const short8*)&aoG[tokA * 64 + 32 + kb];
        }
        short8 f0 = cvt8v(us0, us1), f1 = cvt8v(us2, us3);
        short8 f2 = cvt8v(um0, um1), f3 = cvt8v(um2, um3);

        // h1 = relu([ally | mu | ao] @ H1T + BH1), rows = 2 tok x 8 agents
        f32x4 h[4] = {zero4, zero4, zero4, zero4};
        #pragma unroll
        for (int ks = 0; ks < 6; ++ks) {
            short8 af = (ks == 0) ? f0 : (ks == 1) ? f1 : (ks == 2) ? f2
                      : (ks == 3) ? f3 : (ks == 4) ? ua0 : ua1;
            #pragma unroll
            for (int nt = 0; nt < 4; ++nt) {
                short8 w = *(const short8*)&lH1T[SWZ192(nt * 16 + l15, ks * 32 + kb)];
                h[nt] = MFMA(af, w, h[nt]);
            }
        }
        #pragma unroll
        for (int nt = 0; nt < 4; ++nt) {
            int col = nt * 16 + l15;
            float bh = BH1[col];
            #pragma unroll
            for (int reg = 0; reg < 4; ++reg)
                tile[SWZ64(lg * 4 + reg, col)] = bfr(fmaxf(h[nt][reg] + bh, 0.f));
        }

        // w1 = |h1 @ W2T + b2|
        f32x4 wa = zero4, wb = zero4;
        #pragma unroll
        for (int ks = 0; ks < 2; ++ks) {
            short8 af = *(const short8*)&tile[SWZ64(l15, ks * 32 + kb)];
            short8 b0 = *(const short8*)&lW2T[SWZ64(l15, ks * 32 + kb)];
            short8 b1 = *(const short8*)&lW2T[SWZ64(16 + l15, ks * 32 + kb)];
            wa = MFMA(af, b0, wa);
            wb = MFMA(af, b1, wb);
        }

        // hidden = elu(sum_a qs*|w1| + b1); q = sum_m hidden*wf + v
        float hp0 = 0.f, hp1 = 0.f;
        #pragma unroll
        for (int reg = 0; reg < 4; ++reg) {
            int row = lg * 4 + reg;
            float qsv = agent_qs[(size_t)(T0 + mc * 2 + (row >> 3)) * 8 + (row & 7)];
            hp0 += qsv * fabsf(wa[reg] + b20);
            hp1 += qsv * fabsf(wb[reg] + b21);
        }
        hp0 += __shfl_xor(hp0, 16);
        hp1 += __shfl_xor(hp1, 16);
        int tokL = mc * 2 + (lg >> 1);
        float e0 = hp0 + sB1[wv][tokL * 32 + l15];
        float e1 = hp1 + sB1[wv][tokL * 32 + 16 + l15];
        float hid0 = e0 > 0.f ? e0 : (__expf(e0) - 1.f);
        float hid1 = e1 > 0.f ? e1 : (__expf(e1) - 1.f);
        float q = hid0 * sWF[wv][tokL * 32 + l15]
                + hid1 * sWF[wv][tokL * 32 + 16 + l15];
        q += __shfl_xor(q, 1); q += __shfl_xor(q, 2);
        q += __shfl_xor(q, 4); q += __shfl_xor(q, 8);
        if (l15 == 0 && (lg & 1) == 0)
            out[T0 + tokL] = q + sV[wv][tokL] + vb2;
    }
}

// ---------------------------------------------------------------------------
extern "C" void kernel_launch(void* const* d_in, const int* in_sizes, int n_in,
                              void* d_out, int out_size, void* d_ws, size_t ws_size,
                              hipStream_t stream)
{
    const float* agent_qs = (const float*)d_in[0];
    const float* states   = (const float*)d_in[1];
    const float* mu       = (const float*)d_in[2];
    const float* ally_w   = (const float*)d_in[3];
    const float* ally_b   = (const float*)d_in[4];
    const float* enemy_w  = (const float*)d_in[5];
    const float* enemy_b  = (const float*)d_in[6];
    const float* q_w      = (const float*)d_in[7];
    // d_in[8] = q_b: cancels in softmax over query axis
    const float* k_w      = (const float*)d_in[9];
    const float* k_b      = (const float*)d_in[10];
    const float* hw1_w1   = (const float*)d_in[11];
    const float* hw1_b1   = (const float*)d_in[12];
    const float* hw1_w2   = (const float*)d_in[13];
    const float* hw1_b2   = (const float*)d_in[14];
    const float* hwf_w1   = (const float*)d_in[15];
    const float* hwf_b1   = (const float*)d_in[16];
    const float* hwf_w2   = (const float*)d_in[17];
    const float* hwf_b2   = (const float*)d_in[18];
    const float* hb1_w    = (const float*)d_in[19];
    const float* hb1_b    = (const float*)d_in[20];
    const float* v_w1     = (const float*)d_in[21];
    const float* v_b1     = (const float*)d_in[22];
    const float* v_w2     = (const float*)d_in[23];
    const float* v_b2     = (const float*)d_in[24];
    const float* tre_w    = (const float*)d_in[25];
    const float* tre_b    = (const float*)d_in[26];

    unsigned short* wsb = (unsigned short*)d_ws;
    float* wsf = (float*)((char*)d_ws + (size_t)E_BF16_TOTAL * 2);
    unsigned short* aoG = wsb + E_AO_US;
    float* out = (float*)d_out;

    hipLaunchKernelGGL(qmix_setup, dim3(181), dim3(256), 0, stream,
                       ally_w, enemy_w, q_w, k_w, k_b,
                       hw1_w1, hw1_b1, hw1_w2,
                       hwf_w1, hwf_b1, hwf_w2,
                       hb1_w, hb1_b, v_w1, v_b1, tre_w, tre_b,
                       wsb, wsf);

    hipLaunchKernelGGL(qmix_attn, dim3(TOKS / 8), dim3(512), 0, stream,
                       states, ally_b, enemy_b, wsb, aoG);

    hipLaunchKernelGGL(qmix_hyper, dim3(TOKS / 64), dim3(512), 0, stream,
                       agent_qs, states, mu, v_w2, v_b2, hw1_b2, hwf_b2,
                       wsb, wsf, aoG, out);
}